// Round 1
// baseline (1847.092 us; speedup 1.0000x reference)
//
#include <hip/hip_runtime.h>
#include <math.h>

#define NOBS 1024
#define NX   128
#define NY   256
#define NIT  200

// ---------------------------------------------------------------------------
// K1: Y_hat = X @ W^T + b      grid=(NOBS), block=256 (thread j -> column j)
// ---------------------------------------------------------------------------
__global__ __launch_bounds__(256) void yhat_kernel(const float* __restrict__ X,
                                                   const float* __restrict__ W,
                                                   const float* __restrict__ b,
                                                   float* __restrict__ yhat) {
    __shared__ float xs[NX];
    const int i = blockIdx.x;
    const int j = threadIdx.x;
    if (j < NX) xs[j] = X[i * NX + j];
    __syncthreads();
    const float4* wr = reinterpret_cast<const float4*>(W + j * NX);
    const float4* xr = reinterpret_cast<const float4*>(xs);
    float acc = b[j];
#pragma unroll
    for (int k = 0; k < NX / 4; ++k) {
        float4 w4 = wr[k];
        float4 x4 = xr[k];  // same address across threads -> LDS broadcast
        acc += w4.x * x4.x + w4.y * x4.y + w4.z * x4.z + w4.w * x4.w;
    }
    yhat[i * NY + j] = acc;
}

// ---------------------------------------------------------------------------
// K2: mu[a] = mean_i (Y - Y_hat)[i][a]      grid=(NY), block=256
// ---------------------------------------------------------------------------
__global__ __launch_bounds__(256) void mu_kernel(const float* __restrict__ Y,
                                                 const float* __restrict__ yhat,
                                                 float* __restrict__ mu) {
    const int a = blockIdx.x;
    const int t = threadIdx.x;
    float s = 0.f;
    for (int i = t; i < NOBS; i += 256)
        s += Y[i * NY + a] - yhat[i * NY + a];
#pragma unroll
    for (int off = 32; off; off >>= 1) s += __shfl_xor(s, off);
    __shared__ float red[4];
    if ((t & 63) == 0) red[t >> 6] = s;
    __syncthreads();
    if (t == 0) mu[a] = (red[0] + red[1] + red[2] + red[3]) * (1.0f / NOBS);
}

// ---------------------------------------------------------------------------
// K3: Sigma[a][j] = (1/NOBS) * sum_i epc[i][a]*epc[i][j]   grid=(NY), block=256
// ---------------------------------------------------------------------------
__global__ __launch_bounds__(256) void sigma_kernel(const float* __restrict__ Y,
                                                    const float* __restrict__ yhat,
                                                    const float* __restrict__ mu,
                                                    float* __restrict__ Sigma) {
    const int a = blockIdx.x;
    const int j = threadIdx.x;
    __shared__ float ca[NOBS];
    const float mua = mu[a];
    for (int i = j; i < NOBS; i += 256)
        ca[i] = Y[i * NY + a] - yhat[i * NY + a] - mua;
    __syncthreads();
    const float muj = mu[j];
    float s = 0.f;
#pragma unroll 4
    for (int i = 0; i < NOBS; ++i) {
        float cj = Y[i * NY + j] - yhat[i * NY + j] - muj;
        s += ca[i] * cj;
    }
    Sigma[a * NY + j] = s * (1.0f / NOBS);
}

// ---------------------------------------------------------------------------
// K4: step = 1 / (2*||Sigma||_F + 1e-8)      grid=(1), block=1024
// ---------------------------------------------------------------------------
__global__ __launch_bounds__(1024) void step_kernel(const float* __restrict__ Sigma,
                                                    float* __restrict__ stepv) {
    const int t = threadIdx.x;
    float s = 0.f;
    for (int idx = t; idx < NY * NY; idx += 1024) {
        float v = Sigma[idx];
        s += v * v;
    }
#pragma unroll
    for (int off = 32; off; off >>= 1) s += __shfl_xor(s, off);
    __shared__ float red[16];
    if ((t & 63) == 0) red[t >> 6] = s;
    __syncthreads();
    if (t < 16) {
        float v = red[t];
#pragma unroll
        for (int off = 8; off; off >>= 1) v += __shfl_xor(v, off);
        if (t == 0) stepv[0] = 1.0f / (2.0f * sqrtf(v) + 1e-8f);
    }
}

// ---------------------------------------------------------------------------
// K5: persistent FISTA. grid=(NOBS/4), block=256 (4 waves; wave w projects
// row w). Thread j owns output column j for all 4 rows of its block.
// ---------------------------------------------------------------------------
__global__ __launch_bounds__(256) void fista_kernel(const float* __restrict__ Sigma,
                                                    const float* __restrict__ yhat,
                                                    const float* __restrict__ stepv,
                                                    float* __restrict__ zout) {
    __shared__ float zy[4][NY];  // momentum iterate (also reused to pass v)
    __shared__ float zz[4][NY];  // plain iterate Z
    const int j    = threadIdx.x;
    const int r0   = blockIdx.x * 4;
    const int w    = j >> 6;
    const int lane = j & 63;

    float yh[4];
#pragma unroll
    for (int r = 0; r < 4; ++r) yh[r] = yhat[(r0 + r) * NY + j];
    const float st = stepv[0];

#pragma unroll
    for (int r = 0; r < 4; ++r) {
        zy[r][j] = 1.0f / NY;
        zz[r][j] = 1.0f / NY;
    }
    float tk = 1.0f;
    __syncthreads();

    for (int it = 0; it < NIT; ++it) {
        // ---- grad phase: g[r] = (Zy[r] @ Sigma)[j] ----
        float g0 = 0.f, g1 = 0.f, g2 = 0.f, g3 = 0.f;
        const float* Sp = Sigma + j;
#pragma unroll 4
        for (int k = 0; k < NY; k += 4) {
            float s0 = Sp[(k + 0) * NY];
            float s1 = Sp[(k + 1) * NY];
            float s2 = Sp[(k + 2) * NY];
            float s3 = Sp[(k + 3) * NY];
            float4 a0 = *reinterpret_cast<const float4*>(&zy[0][k]);
            float4 a1 = *reinterpret_cast<const float4*>(&zy[1][k]);
            float4 a2 = *reinterpret_cast<const float4*>(&zy[2][k]);
            float4 a3 = *reinterpret_cast<const float4*>(&zy[3][k]);
            g0 += a0.x * s0 + a0.y * s1 + a0.z * s2 + a0.w * s3;
            g1 += a1.x * s0 + a1.y * s1 + a1.z * s2 + a1.w * s3;
            g2 += a2.x * s0 + a2.y * s1 + a2.z * s2 + a2.w * s3;
            g3 += a3.x * s0 + a3.y * s1 + a3.z * s2 + a3.w * s3;
        }
        // v = Zy - step * (2*g - yhat)
        float v0 = zy[0][j] - st * (2.f * g0 - yh[0]);
        float v1 = zy[1][j] - st * (2.f * g1 - yh[1]);
        float v2 = zy[2][j] - st * (2.f * g2 - yh[2]);
        float v3 = zy[3][j] - st * (2.f * g3 - yh[3]);
        __syncthreads();   // everyone done reading zy
        zy[0][j] = v0;
        zy[1][j] = v1;
        zy[2][j] = v2;
        zy[3][j] = v3;
        __syncthreads();   // v visible to projecting waves

        // ---- projection phase: wave w projects row w onto the simplex ----
        float4 v = *reinterpret_cast<const float4*>(&zy[w][lane * 4]);
        float ps = v.x + v.y + v.z + v.w;
#pragma unroll
        for (int off = 32; off; off >>= 1) ps += __shfl_xor(ps, off);
        float th = (ps - 1.0f) * (1.0f / NY);   // theta0 <= theta*
        for (int nit = 0; nit < 24; ++nit) {    // Newton on f(theta)
            float s = 0.f, c = 0.f, d;
            d = v.x - th; if (d > 0.f) { s += d; c += 1.f; }
            d = v.y - th; if (d > 0.f) { s += d; c += 1.f; }
            d = v.z - th; if (d > 0.f) { s += d; c += 1.f; }
            d = v.w - th; if (d > 0.f) { s += d; c += 1.f; }
#pragma unroll
            for (int off = 32; off; off >>= 1) {
                s += __shfl_xor(s, off);
                c += __shfl_xor(c, off);
            }
            float thn = th + (s - 1.0f) / c;
            if (!(thn > th)) break;             // wave-uniform branch
            th = thn;
        }
        float4 zn;
        zn.x = fmaxf(v.x - th, 0.f);
        zn.y = fmaxf(v.y - th, 0.f);
        zn.z = fmaxf(v.z - th, 0.f);
        zn.w = fmaxf(v.w - th, 0.f);

        // ---- momentum ----
        float tn   = 0.5f * (1.0f + sqrtf(1.0f + 4.0f * tk * tk));
        float beta = (tk - 1.0f) / tn;
        tk = tn;
        float4 zo = *reinterpret_cast<const float4*>(&zz[w][lane * 4]);
        float4 zyn;
        zyn.x = zn.x + beta * (zn.x - zo.x);
        zyn.y = zn.y + beta * (zn.y - zo.y);
        zyn.z = zn.z + beta * (zn.z - zo.z);
        zyn.w = zn.w + beta * (zn.w - zo.w);
        *reinterpret_cast<float4*>(&zz[w][lane * 4]) = zn;
        *reinterpret_cast<float4*>(&zy[w][lane * 4]) = zyn;
        __syncthreads();   // new zy visible before next grad phase
    }

#pragma unroll
    for (int r = 0; r < 4; ++r) zout[(r0 + r) * NY + j] = zz[r][j];
}

// ---------------------------------------------------------------------------
extern "C" void kernel_launch(void* const* d_in, const int* in_sizes, int n_in,
                              void* d_out, int out_size, void* d_ws, size_t ws_size,
                              hipStream_t stream) {
    const float* X = (const float*)d_in[0];
    const float* Y = (const float*)d_in[1];
    const float* W = (const float*)d_in[2];
    const float* b = (const float*)d_in[3];

    float* z_out = (float*)d_out;            // (1024, 256)
    float* yhat  = z_out + NOBS * NY;        // (1024, 256) -- second output

    float* ws    = (float*)d_ws;
    float* mu    = ws;                       // 256
    float* Sigma = ws + NY;                  // 65536
    float* stepv = ws + NY + NY * NY;        // 1

    yhat_kernel<<<NOBS, 256, 0, stream>>>(X, W, b, yhat);
    mu_kernel<<<NY, 256, 0, stream>>>(Y, yhat, mu);
    sigma_kernel<<<NY, 256, 0, stream>>>(Y, yhat, mu, Sigma);
    step_kernel<<<1, 1024, 0, stream>>>(Sigma, stepv);
    fista_kernel<<<NOBS / 4, 256, 0, stream>>>(Sigma, yhat, stepv, z_out);
}

// Round 2
// 457.887 us; speedup vs baseline: 4.0339x; 4.0339x over previous
//
#include <hip/hip_runtime.h>
#include <math.h>

#define NOBS 1024
#define NX   128
#define NY   256
#define NIT  200

typedef _Float16 f16x8 __attribute__((ext_vector_type(8)));
typedef _Float16 f16x4 __attribute__((ext_vector_type(4)));
typedef float    f32x4 __attribute__((ext_vector_type(4)));

// ---------------------------------------------------------------------------
// K1: Y_hat = X @ W^T + b      grid=(NOBS), block=256 (thread j -> column j)
// ---------------------------------------------------------------------------
__global__ __launch_bounds__(256) void yhat_kernel(const float* __restrict__ X,
                                                   const float* __restrict__ W,
                                                   const float* __restrict__ b,
                                                   float* __restrict__ yhat) {
    __shared__ float xs[NX];
    const int i = blockIdx.x;
    const int j = threadIdx.x;
    if (j < NX) xs[j] = X[i * NX + j];
    __syncthreads();
    const float4* wr = reinterpret_cast<const float4*>(W + j * NX);
    const float4* xr = reinterpret_cast<const float4*>(xs);
    float acc = b[j];
#pragma unroll
    for (int k = 0; k < NX / 4; ++k) {
        float4 w4 = wr[k];
        float4 x4 = xr[k];
        acc += w4.x * x4.x + w4.y * x4.y + w4.z * x4.z + w4.w * x4.w;
    }
    yhat[i * NY + j] = acc;
}

// ---------------------------------------------------------------------------
// K2: mu[a] = mean_i (Y - Y_hat)[i][a]      grid=(NY), block=256
// ---------------------------------------------------------------------------
__global__ __launch_bounds__(256) void mu_kernel(const float* __restrict__ Y,
                                                 const float* __restrict__ yhat,
                                                 float* __restrict__ mu) {
    const int a = blockIdx.x;
    const int t = threadIdx.x;
    float s = 0.f;
    for (int i = t; i < NOBS; i += 256)
        s += Y[i * NY + a] - yhat[i * NY + a];
#pragma unroll
    for (int off = 32; off; off >>= 1) s += __shfl_xor(s, off);
    __shared__ float red[4];
    if ((t & 63) == 0) red[t >> 6] = s;
    __syncthreads();
    if (t == 0) mu[a] = (red[0] + red[1] + red[2] + red[3]) * (1.0f / NOBS);
}

// ---------------------------------------------------------------------------
// K3: Sigma[a][j] = (1/NOBS) * sum_i epc[i][a]*epc[i][j]   grid=(NY), block=256
// ---------------------------------------------------------------------------
__global__ __launch_bounds__(256) void sigma_kernel(const float* __restrict__ Y,
                                                    const float* __restrict__ yhat,
                                                    const float* __restrict__ mu,
                                                    float* __restrict__ Sigma) {
    const int a = blockIdx.x;
    const int j = threadIdx.x;
    __shared__ float ca[NOBS];
    const float mua = mu[a];
    for (int i = j; i < NOBS; i += 256)
        ca[i] = Y[i * NY + a] - yhat[i * NY + a] - mua;
    __syncthreads();
    const float muj = mu[j];
    float s = 0.f;
#pragma unroll 4
    for (int i = 0; i < NOBS; ++i) {
        float cj = Y[i * NY + j] - yhat[i * NY + j] - muj;
        s += ca[i] * cj;
    }
    Sigma[a * NY + j] = s * (1.0f / NOBS);
}

// ---------------------------------------------------------------------------
// K4: step = 1 / (2*||Sigma||_F + 1e-8)      grid=(1), block=1024
// ---------------------------------------------------------------------------
__global__ __launch_bounds__(1024) void step_kernel(const float* __restrict__ Sigma,
                                                    float* __restrict__ stepv) {
    const int t = threadIdx.x;
    float s = 0.f;
    for (int idx = t; idx < NY * NY; idx += 1024) {
        float v = Sigma[idx];
        s += v * v;
    }
#pragma unroll
    for (int off = 32; off; off >>= 1) s += __shfl_xor(s, off);
    __shared__ float red[16];
    if ((t & 63) == 0) red[t >> 6] = s;
    __syncthreads();
    if (t < 16) {
        float v = red[t];
#pragma unroll
        for (int off = 8; off; off >>= 1) v += __shfl_xor(v, off);
        if (t == 0) stepv[0] = 1.0f / (2.0f * sqrtf(v) + 1e-8f);
    }
}

// ---------------------------------------------------------------------------
// K5: persistent FISTA via MFMA. grid=(NOBS/4) blocks, 256 threads (4 waves).
// Block owns 4 rows. Wave w owns output columns [64w, 64w+64) for the grad
// GEMM (B-slice of Sigma in f16 registers, 128 VGPR) and projects row w.
// A (Zy, f16) lives in a 16x256 XOR-swizzled LDS tile (rows 4..15 zero).
// ---------------------------------------------------------------------------
__global__ __launch_bounds__(256, 1) void fista_mfma_kernel(
        const float* __restrict__ Sigma,
        const float* __restrict__ yhat,
        const float* __restrict__ stepv,
        float* __restrict__ zout) {
    __shared__ _Float16 zyA[16 * 256];   // A matrix, swizzled: byte ^= (row&7)<<4
    __shared__ float    vbuf[4 * 256];   // fp32 zy / v scratch

    const int tid  = threadIdx.x;
    const int w    = tid >> 6;           // wave id = column-slice id = row id
    const int lane = tid & 63;
    const int r0   = blockIdx.x * 4;

    const float st  = stepv[0];
    const float st2 = 2.0f * st;

    // ---- init LDS ----
    {
        f16x8 zv = {0, 0, 0, 0, 0, 0, 0, 0};
        for (int i = tid; i < 16 * 256 / 8; i += 256)
            *reinterpret_cast<f16x8*>(zyA + i * 8) = zv;
    }
    __syncthreads();
    {
        const _Float16 u = (_Float16)(1.0f / 256.0f);
        for (int i = tid; i < 4 * 256; i += 256) {   // rows 0..3 (uniform fill:
            zyA[i]  = u;                             //  swizzle-invariant)
            vbuf[i] = 1.0f / 256.0f;
        }
    }

    // ---- preload B fragments: B[k][col] = Sigma[col][k] (symmetry) ----
    const int colg = w * 64 + (lane & 15);
    const int ksub = (lane >> 4) * 8;
    f16x8 bfr[4][8];
#pragma unroll
    for (int n = 0; n < 4; ++n) {
#pragma unroll
        for (int kk = 0; kk < 8; ++kk) {
            const float* p = Sigma + (colg + n * 16) * NY + kk * 32 + ksub;
            float4 lo = *reinterpret_cast<const float4*>(p);
            float4 hi = *reinterpret_cast<const float4*>(p + 4);
            f16x8 bv;
            bv[0] = (_Float16)lo.x; bv[1] = (_Float16)lo.y;
            bv[2] = (_Float16)lo.z; bv[3] = (_Float16)lo.w;
            bv[4] = (_Float16)hi.x; bv[5] = (_Float16)hi.y;
            bv[6] = (_Float16)hi.z; bv[7] = (_Float16)hi.w;
            bfr[n][kk] = bv;
        }
    }

    // ---- preload st * yhat for the epilogue (lanes 0..15 only) ----
    float styh[16];
    if (lane < 16) {
#pragma unroll
        for (int r = 0; r < 4; ++r)
#pragma unroll
            for (int n = 0; n < 4; ++n)
                styh[r * 4 + n] = st * yhat[(r0 + r) * NY + w * 64 + n * 16 + lane];
    }

    f32x4 zz = {1.0f / 256.0f, 1.0f / 256.0f, 1.0f / 256.0f, 1.0f / 256.0f};
    float tk = 1.0f;
    float th = 0.0f;                      // warm-started simplex threshold
    __syncthreads();

    for (int it = 0; it < NIT; ++it) {
        // ---- grad phase: acc[n] = (Zy @ Sigma) tile (16x16), K=256 ----
        f32x4 acc[4] = {{0,0,0,0},{0,0,0,0},{0,0,0,0},{0,0,0,0}};
        const int arow  = lane & 15;
        const int abase = arow * 512;
        const int aswz  = (arow & 7) << 4;
#pragma unroll
        for (int kk = 0; kk < 8; ++kk) {
            const int aoff = (kk * 64 + (lane >> 4) * 16) ^ aswz;
            f16x8 af = *reinterpret_cast<const f16x8*>(
                reinterpret_cast<const char*>(zyA) + abase + aoff);
#pragma unroll
            for (int n = 0; n < 4; ++n)
                acc[n] = __builtin_amdgcn_mfma_f32_16x16x32_f16(af, bfr[n][kk],
                                                                acc[n], 0, 0, 0);
        }
        // ---- epilogue: v = zy - st*(2g - yhat); lanes 0..15 hold rows 0..3 ----
        if (lane < 16) {
#pragma unroll
            for (int r = 0; r < 4; ++r) {
#pragma unroll
                for (int n = 0; n < 4; ++n) {
                    const int c = w * 64 + n * 16 + lane;
                    float zyo = vbuf[r * 256 + c];
                    vbuf[r * 256 + c] = zyo - st2 * acc[n][r] + styh[r * 4 + n];
                }
            }
        }
        __syncthreads();

        // ---- projection: wave w projects row w onto the simplex ----
        f32x4 v4 = *reinterpret_cast<const f32x4*>(vbuf + w * 256 + lane * 4);
        float ps = v4[0] + v4[1] + v4[2] + v4[3];
#pragma unroll
        for (int off = 32; off; off >>= 1) ps += __shfl_xor(ps, off);
        const float th0 = (ps - 1.0f) * (1.0f / 256.0f);   // always <= theta*

        for (int nit = 0; nit < 16; ++nit) {
            float s = 0.f, c = 0.f, d;
            d = v4[0] - th; if (d > 0.f) { s += d; c += 1.f; }
            d = v4[1] - th; if (d > 0.f) { s += d; c += 1.f; }
            d = v4[2] - th; if (d > 0.f) { s += d; c += 1.f; }
            d = v4[3] - th; if (d > 0.f) { s += d; c += 1.f; }
#pragma unroll
            for (int off = 32; off; off >>= 1) {
                s += __shfl_xor(s, off);
                c += __shfl_xor(c, off);
            }
            if (c < 0.5f) { th = th0; continue; }   // overshot support: restart low
            if (fabsf(s - 1.0f) <= 1e-6f) break;    // converged (exact segment)
            th += (s - 1.0f) / c;                   // Newton (finite convergence)
        }

        f32x4 zn;
        zn[0] = fmaxf(v4[0] - th, 0.f);
        zn[1] = fmaxf(v4[1] - th, 0.f);
        zn[2] = fmaxf(v4[2] - th, 0.f);
        zn[3] = fmaxf(v4[3] - th, 0.f);

        const float tn   = 0.5f * (1.0f + sqrtf(1.0f + 4.0f * tk * tk));
        const float beta = (tk - 1.0f) / tn;
        tk = tn;
        f32x4 zyn;
        zyn[0] = zn[0] + beta * (zn[0] - zz[0]);
        zyn[1] = zn[1] + beta * (zn[1] - zz[1]);
        zyn[2] = zn[2] + beta * (zn[2] - zz[2]);
        zyn[3] = zn[3] + beta * (zn[3] - zz[3]);
        zz = zn;

        // write zyn: fp32 -> vbuf, f16 -> zyA (swizzled row w)
        *reinterpret_cast<f32x4*>(vbuf + w * 256 + lane * 4) = zyn;
        {
            const int off = (lane * 8) ^ ((w & 7) << 4);
            f16x4 hz;
            hz[0] = (_Float16)zyn[0]; hz[1] = (_Float16)zyn[1];
            hz[2] = (_Float16)zyn[2]; hz[3] = (_Float16)zyn[3];
            *reinterpret_cast<f16x4*>(
                reinterpret_cast<char*>(zyA) + w * 512 + off) = hz;
        }
        __syncthreads();
    }

    // ---- output: zz of wave w is row r0+w ----
    *reinterpret_cast<f32x4*>(zout + (r0 + w) * NY + lane * 4) = zz;
}

// ---------------------------------------------------------------------------
extern "C" void kernel_launch(void* const* d_in, const int* in_sizes, int n_in,
                              void* d_out, int out_size, void* d_ws, size_t ws_size,
                              hipStream_t stream) {
    const float* X = (const float*)d_in[0];
    const float* Y = (const float*)d_in[1];
    const float* W = (const float*)d_in[2];
    const float* b = (const float*)d_in[3];

    float* z_out = (float*)d_out;            // (1024, 256)
    float* yhat  = z_out + NOBS * NY;        // (1024, 256) -- second output

    float* ws    = (float*)d_ws;
    float* mu    = ws;                       // 256
    float* Sigma = ws + NY;                  // 65536
    float* stepv = ws + NY + NY * NY;        // 1

    yhat_kernel<<<NOBS, 256, 0, stream>>>(X, W, b, yhat);
    mu_kernel<<<NY, 256, 0, stream>>>(Y, yhat, mu);
    sigma_kernel<<<NY, 256, 0, stream>>>(Y, yhat, mu, Sigma);
    step_kernel<<<1, 1024, 0, stream>>>(Sigma, stepv);
    fista_mfma_kernel<<<NOBS / 4, 256, 0, stream>>>(Sigma, yhat, stepv, z_out);
}